// Round 8
// baseline (305.753 us; speedup 1.0000x reference)
//
#include <hip/hip_runtime.h>
#include <hip/hip_fp16.h>
#include <math.h>

#define NN 50000
#define NE 800000
#define ET (NE + NN)
#define NG 64
#define H 4
#define NBK 196                   // dst buckets (dst >> 8)
#define CH 2048                   // edges per chunk
#define SB ((ET + CH - 1) / CH)   // 416 edge chunks
#define GD ((NN + 63) / 64)       // dualgemm grid (782)

typedef _Float16 half8 __attribute__((ext_vector_type(8)));
typedef _Float16 half4 __attribute__((ext_vector_type(4)));
typedef _Float16 hv2 __attribute__((ext_vector_type(2)));
typedef float floatx4 __attribute__((ext_vector_type(4)));

// ---------------- weight prep device fn ----------------

template <int K, int M2>
__device__ __forceinline__ void wprep_fn(int chunk, const float* __restrict__ Wl, const float* __restrict__ Wr,
                                         _Float16* __restrict__ Wfrag) {
    constexpr int MTOT = 2 * M2, NT = MTOT / 16;
    if (chunk >= MTOT * K / 8) return;
    int lane = chunk & 63, tt = chunk >> 6;
    int t = tt % NT, kt = tt / NT;
    int n = t * 16 + (lane & 15);
    int kb = kt * 32 + (lane >> 4) * 8;
    const float* src = (n < M2) ? (Wl + n) : (Wr + (n - M2));
    half8 h;
#pragma unroll
    for (int j = 0; j < 8; ++j) h[j] = (_Float16)src[(size_t)(kb + j) * M2];
    *(half8*)(Wfrag + (size_t)chunk * 8) = h;
}

// ---------------- fused prep: wprep (26) + bounds (196) + bhist (416) ----------------

__global__ __launch_bounds__(256) void k_prep(const float* __restrict__ Wl1, const float* __restrict__ Wr1,
                                              const float* __restrict__ Wl2, const float* __restrict__ Wr2,
                                              const float* __restrict__ Wl3, const float* __restrict__ Wr3,
                                              _Float16* __restrict__ Wf1, _Float16* __restrict__ Wf2,
                                              _Float16* __restrict__ Wf3,
                                              const int* __restrict__ batch, int* __restrict__ bpos,
                                              const int* __restrict__ ei, int* __restrict__ bcnt) {
    int b = blockIdx.x, t = threadIdx.x;
    if (b < 16) { wprep_fn<128, 128>(b * 256 + t, Wl1, Wr1, Wf1); return; }
    if (b < 24) { wprep_fn<128, 64>((b - 16) * 256 + t, Wl2, Wr2, Wf2); return; }
    if (b < 26) { wprep_fn<64, 32>((b - 24) * 256 + t, Wl3, Wr3, Wf3); return; }
    if (b < 26 + NBK) {
        int i = (b - 26) * 256 + t;
        if (i >= NN) return;
        int cur = batch[i];
        int prev = (i == 0) ? -1 : batch[i - 1];
        for (int g = prev + 1; g <= cur; ++g) bpos[g] = i;
        if (i == NN - 1)
            for (int g = cur + 1; g <= NG; ++g) bpos[g] = NN;
        return;
    }
    // bhist
    __shared__ int hist[NBK];
    int b0 = b - 26 - NBK;
    for (int i = t; i < NBK; i += 256) hist[i] = 0;
    __syncthreads();
#pragma unroll
    for (int pass = 0; pass < CH / 256; ++pass) {
        int e = b0 * CH + pass * 256 + t;
        if (e < ET) {
            int d = (e < NE) ? ei[NE + e] : (e - NE);
            atomicAdd(&hist[d >> 8], 1);
        }
    }
    __syncthreads();
    if (t < NBK) bcnt[t * SB + b0] = hist[t];
}

// ---------------- dualgemm body; A fp16/fp32; optional fused GraphNorm on A
//                  (params computed per-block into LDS from sum/sumsq) ----------------

template <typename AT, bool NORM>
__device__ __forceinline__ half8 load_a8(const AT* __restrict__ ap, const float* pa, const float* pb) {
    if constexpr (NORM) {
        half8 raw = *(const half8*)ap;
        half8 h;
#pragma unroll
        for (int j = 0; j < 8; ++j) {
            float y = fmaf((float)raw[j], pa[j], pb[j]);
            h[j] = (_Float16)fmaxf(y, 0.f);
        }
        return h;
    } else if constexpr (__is_same(AT, _Float16)) {
        return *(const half8*)ap;
    } else {
        const float4* p = (const float4*)ap;
        float4 a = p[0], b = p[1];
        half8 h;
        h[0] = (_Float16)a.x; h[1] = (_Float16)a.y; h[2] = (_Float16)a.z; h[3] = (_Float16)a.w;
        h[4] = (_Float16)b.x; h[5] = (_Float16)b.y; h[6] = (_Float16)b.z; h[7] = (_Float16)b.w;
        return h;
    }
}

template <int K, int M2, typename AT, bool NORM>
__device__ __forceinline__ void dualgemm_body(int blk, int tid, const AT* __restrict__ Ain,
                                              const _Float16* __restrict__ Wfrag,
                                              __half* __restrict__ Ol, __half* __restrict__ Or,
                                              const float* __restrict__ gsum, const float* __restrict__ gsq,
                                              const float* __restrict__ gw, const float* __restrict__ gbb,
                                              const float* __restrict__ gms,
                                              const int* __restrict__ bpos, const int* __restrict__ batch) {
    constexpr int MTOT = 2 * M2;
    constexpr int NT = MTOT / 16;
    constexpr int KT = K / 32;
    constexpr int PK = NORM ? K : 1;      // LDS param table width
    __shared__ float spab[2][8][PK];      // [a|bsh][graph-local][channel]
    int wid = tid >> 6, lane = tid & 63;
    int q = lane >> 4, l15 = lane & 15;
    int r0 = blk * 64 + wid * 16;
    int arow = min(r0 + l15, NN - 1);
    const AT* ap = Ain + (size_t)arow * K + q * 8;
    const float *pa = nullptr, *pb = nullptr;
    if constexpr (NORM) {
        // block rows span graphs [g0, g1]; graphs are ~780 rows so gspan <= 2 in practice
        int rb = blk * 64;
        int g0 = batch[min(rb, NN - 1)];
        int g1 = batch[min(rb + 63, NN - 1)];
        int gspan = min(g1 - g0 + 1, 8);
        for (int i = tid; i < gspan * K; i += 256) {
            int gg = i / K, c = i - gg * K;
            int g = g0 + gg;
            float cg = fmaxf((float)(bpos[g + 1] - bpos[g]), 1.f);
            float mu = gsum[(size_t)g * K + c] / cg;
            float ex2 = gsq[(size_t)g * K + c] / cg;
            float s_ = gms[c];
            float var = ex2 - s_ * (2.f - s_) * mu * mu;
            float a = rsqrtf(var + 1e-5f) * gw[c];
            spab[0][gg][c] = a;
            spab[1][gg][c] = gbb[c] - mu * s_ * a;
        }
        __syncthreads();
        int gg = min(batch[arow] - g0, 7);
        pa = &spab[0][gg][q * 8];
        pb = &spab[1][gg][q * 8];
    }

    floatx4 acc[NT];
#pragma unroll
    for (int t = 0; t < NT; ++t) acc[t] = (floatx4){0.f, 0.f, 0.f, 0.f};

#pragma unroll
    for (int kt = 0; kt < KT; ++kt) {
        half8 a8 = load_a8<AT, NORM>(ap + kt * 32, pa + (NORM ? kt * 32 : 0), pb + (NORM ? kt * 32 : 0));
        const _Float16* wp = Wfrag + ((size_t)(kt * NT) * 64 + lane) * 8;
#pragma unroll
        for (int t = 0; t < NT; ++t) {
            half8 b8 = *(const half8*)(wp + (size_t)t * 64 * 8);
            acc[t] = __builtin_amdgcn_mfma_f32_16x16x32_f16(a8, b8, acc[t], 0, 0, 0);
        }
    }

#pragma unroll
    for (int t = 0; t < NT; ++t) {
        int cn = t * 16 + l15;
#pragma unroll
        for (int reg = 0; reg < 4; ++reg) {
            int r = r0 + q * 4 + reg;
            if (r < NN) {
                if (cn < M2) Ol[(size_t)r * M2 + cn] = __float2half(acc[t][reg]);
                else         Or[(size_t)r * M2 + (cn - M2)] = __float2half(acc[t][reg]);
            }
        }
    }
}

template <int K, int M2>
__global__ __launch_bounds__(256) void k_dualgemm_n(const __half* __restrict__ Ain,
                                                    const _Float16* __restrict__ Wfrag,
                                                    __half* __restrict__ Ol, __half* __restrict__ Or,
                                                    const float* __restrict__ gsum, const float* __restrict__ gsq,
                                                    const float* __restrict__ gw, const float* __restrict__ gbb,
                                                    const float* __restrict__ gms,
                                                    const int* __restrict__ bpos, const int* __restrict__ batch) {
    dualgemm_body<K, M2, _Float16, true>(blockIdx.x, threadIdx.x, (const _Float16*)Ain, Wfrag, Ol, Or,
                                         gsum, gsq, gw, gbb, gms, bpos, batch);
}

// ---------------- bscanA device fn: pair-scan of SB(416) chunk-counts per bucket ----------------

__device__ __forceinline__ void bscanA_fn(int b, int t, const int* __restrict__ bcnt,
                                          int* __restrict__ boff, int* __restrict__ tot) {
    __shared__ int lds[256];
    int i0 = 2 * t, i1 = 2 * t + 1;
    int v0 = (i0 < SB) ? bcnt[b * SB + i0] : 0;
    int v1 = (i1 < SB) ? bcnt[b * SB + i1] : 0;
    int pair = v0 + v1;
    lds[t] = pair;
    __syncthreads();
    for (int off = 1; off < 256; off <<= 1) {
        int y = (t >= off) ? lds[t - off] : 0;
        __syncthreads();
        lds[t] += y;
        __syncthreads();
    }
    int excl = lds[t] - pair;
    if (i0 < SB) boff[b * SB + i0] = excl;
    if (i1 < SB) boff[b * SB + i1] = excl + v0;
    if (t == 255) tot[b] = lds[255];
}

// ---- fused: dualgemm l1 (782 blocks, fp32 input) + bscanA (196 blocks)

__global__ __launch_bounds__(256) void k_gemm1_scan(const float* __restrict__ x, const _Float16* __restrict__ Wf1,
                                                    __half* __restrict__ Ol, __half* __restrict__ Or,
                                                    const int* __restrict__ bcnt, int* __restrict__ boff,
                                                    int* __restrict__ tot) {
    if (blockIdx.x < GD)
        dualgemm_body<128, 128, float, false>(blockIdx.x, threadIdx.x, x, Wf1, Ol, Or,
                                              nullptr, nullptr, nullptr, nullptr, nullptr, nullptr, nullptr);
    else
        bscanA_fn(blockIdx.x - GD, threadIdx.x, bcnt, boff, tot);
}

// ---------------- CSR: scatter into bucket-major ebuf (1024 threads) ----------------

__device__ __forceinline__ void edge_sd(int e, const int* __restrict__ ei, int& s, int& d) {
    if (e < NE) { s = ei[e]; d = ei[NE + e]; } else { s = e - NE; d = s; }
}

__global__ __launch_bounds__(1024) void k_bscatter(const int* __restrict__ ei, const int* __restrict__ tot,
                                                   const int* __restrict__ boff, unsigned int* __restrict__ ebuf) {
    __shared__ int eb[256];
    __shared__ int cur[NBK];
    int b0 = blockIdx.x, t = threadIdx.x;
    int v = (t < NBK) ? tot[t] : 0;
    if (t < 256) eb[t] = v;
    __syncthreads();
    for (int off = 1; off < 256; off <<= 1) {
        int y = (t >= off && t < 256) ? eb[t - off] : 0;
        __syncthreads();
        if (t < 256) eb[t] += y;
        __syncthreads();
    }
    if (t < NBK) cur[t] = (eb[t] - v) + boff[t * SB + b0];
    __syncthreads();
#pragma unroll
    for (int pass = 0; pass < CH / 1024; ++pass) {
        int e = b0 * CH + pass * 1024 + t;
        if (e < ET) {
            int s, d;
            edge_sd(e, ei, s, d);
            int pos = atomicAdd(&cur[d >> 8], 1);
            ebuf[pos] = ((unsigned)s << 16) | (unsigned)(d & 255);
        }
    }
}

// ---------------- CSR: per-bucket counting sort -> rowptr + colsrc + within-bucket degree-sorted perm ----------------

__global__ __launch_bounds__(1024) void k_bsort(const unsigned int* __restrict__ ebuf,
                                                const int* __restrict__ tot,
                                                int* __restrict__ rowptr, unsigned short* __restrict__ colsrc,
                                                int* __restrict__ perm) {
    __shared__ int eb[256];
    __shared__ int sbase;
    __shared__ int cnt2[256];
    __shared__ int sc[256];
    __shared__ int cur2[256];
    int b = blockIdx.x, t = threadIdx.x;
    int v = (t < NBK) ? tot[t] : 0;
    if (t < 256) eb[t] = v;
    __syncthreads();
    for (int off = 1; off < 256; off <<= 1) {
        int y = (t >= off && t < 256) ? eb[t - off] : 0;
        __syncthreads();
        if (t < 256) eb[t] += y;
        __syncthreads();
    }
    if (t == b) sbase = eb[t] - v;   // b < NBK <= 255
    __syncthreads();
    int base = sbase, n = tot[b];
    if (t < 256) cnt2[t] = 0;
    __syncthreads();
    for (int i = t; i < n; i += 1024) atomicAdd(&cnt2[ebuf[base + i] & 255], 1);
    __syncthreads();
    if (t < 256) sc[t] = cnt2[t];
    __syncthreads();
    for (int off = 1; off < 256; off <<= 1) {
        int y = (t >= off && t < 256) ? sc[t - off] : 0;
        __syncthreads();
        if (t < 256) sc[t] += y;
        __syncthreads();
    }
    int valid = min(NN - b * 256, 256);
    if (t < 256) {
        int cv = cnt2[t];
        int excl = sc[t] - cv;
        int d = b * 256 + t;
        if (d < NN) rowptr[d] = base + excl;
        cur2[t] = excl;
    }
    if (b == 0 && t == 0) rowptr[NN] = ET;
    __syncthreads();
    // within-bucket degree-sort perm: wave-load-balance for attn without losing locality.
    // rank[t] = #{u valid : deg[u] < deg[t] or (== and u < t)}  (stable -> permutation)
    if (t < valid) {
        int dv = cnt2[t];
        int rank = 0;
        for (int u = 0; u < valid; ++u) {
            int du = cnt2[u];
            rank += (du < dv) || (du == dv && u < t);
        }
        perm[b * 256 + rank] = b * 256 + t;
    }
    for (int i = t; i < n; i += 1024) {
        unsigned u = ebuf[base + i];
        int pos = atomicAdd(&cur2[u & 255], 1);
        colsrc[base + pos] = (unsigned short)(u >> 16);
    }
}

// ---------------- GATv2 attention: channel-split + packed fp16 + no-max softmax, fp16 output ----------------

template <int CP> struct HVec { hv2 h2[CP / 2]; };

template <int CP>
__device__ __forceinline__ HVec<CP> load_hv(const __half* __restrict__ p) {
    HVec<CP> r;
    if constexpr (CP == 16) {
        float4* rp = (float4*)&r;
        rp[0] = ((const float4*)p)[0];
        rp[1] = ((const float4*)p)[1];
    } else if constexpr (CP == 8) {
        float4 t = *(const float4*)p; r = *(HVec<CP>*)&t;
    } else if constexpr (CP == 4) {
        float2 t = *(const float2*)p; r = *(HVec<CP>*)&t;
    } else {
        r.h2[0] = *(const hv2*)p;
    }
    return r;
}

template <int C, int EP, bool CONCAT>
__global__ __launch_bounds__(256) void k_attn(const __half* __restrict__ xl, const __half* __restrict__ xr,
                                              const int* __restrict__ rowptr,
                                              const unsigned short* __restrict__ colsrc,
                                              const int* __restrict__ perm,
                                              const float* __restrict__ att, const float* __restrict__ bias,
                                              __half* __restrict__ out) {
    constexpr int CP = C / EP;
    constexpr int LEP = (EP == 4) ? 2 : ((EP == 2) ? 1 : 0);
    int t = blockIdx.x * 256 + threadIdx.x;
    int part = t & (EP - 1);
    int nh = t >> LEP;
    if (nh >= NN * H) return;
    int node = perm[nh >> 2];                 // within-bucket degree-sorted order
    int h = nh & 3;                           // H == 4
    int cbase = h * C + part * CP;
    hv2 xrr2[CP / 2], attv2[CP / 2];
    float acc[CP];
    {
        HVec<CP> xrv = load_hv<CP>(xr + (size_t)node * (H * C) + cbase);
        const float* q = att + cbase;
#pragma unroll
        for (int j = 0; j < CP / 2; ++j) {
            xrr2[j] = xrv.h2[j];
            attv2[j] = (hv2){(_Float16)q[2 * j], (_Float16)q[2 * j + 1]};
        }
#pragma unroll
        for (int c = 0; c < CP; ++c) acc[c] = 0.f;
    }
    float denom = 0.f;
    int beg = rowptr[node], end = rowptr[node + 1];

    auto process = [&](const HVec<CP>& xv) {
        float part_s = 0.f;
#pragma unroll
        for (int j = 0; j < CP / 2; ++j) {
            hv2 z = xv.h2[j] + xrr2[j];
            hv2 l = __builtin_elementwise_max(z, z * (_Float16)0.2f);   // leaky_relu
            part_s = __builtin_amdgcn_fdot2(l, attv2[j], part_s, false);
        }
        float score = part_s;
#pragma unroll
        for (int mask = 1; mask < EP; mask <<= 1) score += __shfl_xor(score, mask, 64);
        float w = __expf(score);
        denom += w;
        const _Float16* xh = (const _Float16*)&xv;
#pragma unroll
        for (int c = 0; c < CP; ++c) acc[c] = fmaf(w, (float)xh[c], acc[c]);
    };

    int idx = beg;
    // 8-wide main loop: issue all 8 gathers before consuming (MLP for latency-bound gather)
    for (; idx + 8 <= end; idx += 8) {
        int s[8];
#pragma unroll
        for (int u = 0; u < 8; ++u) s[u] = colsrc[idx + u];
        HVec<CP> xv[8];
#pragma unroll
        for (int u = 0; u < 8; ++u) xv[u] = load_hv<CP>(xl + (size_t)s[u] * (H * C) + cbase);
#pragma unroll
        for (int u = 0; u < 8; ++u) process(xv[u]);
    }
    for (; idx + 4 <= end; idx += 4) {
        int s0 = colsrc[idx], s1 = colsrc[idx + 1], s2 = colsrc[idx + 2], s3 = colsrc[idx + 3];
        HVec<CP> xv0 = load_hv<CP>(xl + (size_t)s0 * (H * C) + cbase);
        HVec<CP> xv1 = load_hv<CP>(xl + (size_t)s1 * (H * C) + cbase);
        HVec<CP> xv2 = load_hv<CP>(xl + (size_t)s2 * (H * C) + cbase);
        HVec<CP> xv3 = load_hv<CP>(xl + (size_t)s3 * (H * C) + cbase);
        process(xv0);
        process(xv1);
        process(xv2);
        process(xv3);
    }
    for (; idx < end; ++idx) {
        int s = colsrc[idx];
        HVec<CP> xv = load_hv<CP>(xl + (size_t)s * (H * C) + cbase);
        process(xv);
    }

    float inv = 1.f / denom;
    _Float16* op = (_Float16*)out + (size_t)node * (H * C) + cbase;
    _Float16 hv[CP];
#pragma unroll
    for (int c = 0; c < CP; ++c) {
        float v = acc[c] * inv;
        if (CONCAT) v += bias[cbase + c];
        hv[c] = (_Float16)v;
    }
    if constexpr (CP >= 8) {
#pragma unroll
        for (int j = 0; j < CP / 8; ++j) *(half8*)(op + 8 * j) = *(half8*)(hv + 8 * j);
    } else if constexpr (CP == 4) {
        *(half4*)op = *(half4*)hv;
    } else {
        *(hv2*)op = *(hv2*)hv;
    }
}

// ---------------- GraphNorm reduce (fp16 input): one block per (graph, segment) ----------------

template <int LOGC, int SPLIT>
__global__ __launch_bounds__(256) void k_gnred2(const __half* __restrict__ h, const int* __restrict__ bpos,
                                                float* __restrict__ sum, float* __restrict__ sumsq) {
    constexpr int C = 1 << LOGC;
    constexpr int RG = 256 >> LOGC;      // row-groups per block
    int g = blockIdx.x / SPLIT, s = blockIdx.x % SPLIT;
    int c = threadIdx.x & (C - 1);
    int rg = threadIdx.x >> LOGC;
    int b0 = bpos[g], b1 = bpos[g + 1];
    int n = b1 - b0;
    int seg = (n + SPLIT - 1) / SPLIT;
    int r0 = b0 + s * seg;
    int r1 = min(r0 + seg, b1);
    float sv = 0.f, ssv = 0.f;
    for (int r = r0 + rg; r < r1; r += RG) {
        float x = __half2float(h[(size_t)r * C + c]);
        sv += x; ssv += x * x;
    }
    __shared__ float ls[256], lss[256];
    ls[threadIdx.x] = sv; lss[threadIdx.x] = ssv;
    __syncthreads();
    for (int off = 128; off >= C; off >>= 1) {
        if (threadIdx.x < off) {
            ls[threadIdx.x] += ls[threadIdx.x + off];
            lss[threadIdx.x] += lss[threadIdx.x + off];
        }
        __syncthreads();
    }
    if (threadIdx.x < C) {
        atomicAdd(&sum[g * C + threadIdx.x], ls[threadIdx.x]);
        atomicAdd(&sumsq[g * C + threadIdx.x], lss[threadIdx.x]);
    }
}

// ---------------- fused layer-3 tail: head-mean + bias + GN3 stats ----------------

template <int SPLIT>
__global__ __launch_bounds__(256) void k_headgn(const __half* __restrict__ tmp, const float* __restrict__ b3,
                                                const int* __restrict__ bpos, float* __restrict__ Af,
                                                float* __restrict__ sum, float* __restrict__ sumsq) {
    constexpr int C = 8, RG = 32;
    int g = blockIdx.x / SPLIT, s = blockIdx.x % SPLIT;
    int c = threadIdx.x & 7;
    int rg = threadIdx.x >> 3;
    int b0 = bpos[g], b1 = bpos[g + 1];
    int n = b1 - b0;
    int seg = (n + SPLIT - 1) / SPLIT;
    int r0 = b0 + s * seg;
    int r1 = min(r0 + seg, b1);
    float bias = b3[c];
    float sv = 0.f, ssv = 0.f;
    for (int r = r0 + rg; r < r1; r += RG) {
        const __half* p = tmp + (size_t)r * 32 + c;
        float v = 0.25f * (__half2float(p[0]) + __half2float(p[8]) +
                           __half2float(p[16]) + __half2float(p[24])) + bias;
        Af[(size_t)r * C + c] = v;
        sv += v; ssv += v * v;
    }
    __shared__ float ls[256], lss[256];
    ls[threadIdx.x] = sv; lss[threadIdx.x] = ssv;
    __syncthreads();
    for (int off = 128; off >= C; off >>= 1) {
        if (threadIdx.x < off) {
            ls[threadIdx.x] += ls[threadIdx.x + off];
            lss[threadIdx.x] += lss[threadIdx.x + off];
        }
        __syncthreads();
    }
    if (threadIdx.x < C) {
        atomicAdd(&sum[g * C + threadIdx.x], ls[threadIdx.x]);
        atomicAdd(&sumsq[g * C + threadIdx.x], lss[threadIdx.x]);
    }
}

// ---------------- GN3 normalize + relu + pool + mean + linear head (one block per graph) ----------------

__global__ __launch_bounds__(256) void k_gnpool_final(const float* __restrict__ Af, const int* __restrict__ bpos,
                                                      const float* __restrict__ sum, const float* __restrict__ sumsq,
                                                      const float* __restrict__ w,
                                                      const float* __restrict__ b, const float* __restrict__ ms,
                                                      const float* __restrict__ lw, const float* __restrict__ lb,
                                                      float* __restrict__ outp) {
    constexpr int C = 8, RG = 32;
    int g = blockIdx.x;
    int c = threadIdx.x & 7;
    int rg = threadIdx.x >> 3;
    int b0 = bpos[g], b1 = bpos[g + 1];
    int n = b1 - b0;
    float cg = fmaxf((float)n, 1.f);
    float mu = sum[g * C + c] / cg;
    float ex2 = sumsq[g * C + c] / cg;
    float s_ = ms[c];
    float var = ex2 - (2.f * s_ - s_ * s_) * mu * mu;
    float rs = rsqrtf(var + 1e-5f) * w[c];
    float bb = b[c], mus = mu * s_;
    float pv = 0.f;
    for (int r = b0 + rg; r < b1; r += RG) {
        float y = fmaxf((Af[(size_t)r * C + c] - mus) * rs + bb, 0.f);
        pv += y;
    }
    __shared__ float ls[256];
    __shared__ float feat[8];
    ls[threadIdx.x] = pv;
    __syncthreads();
    for (int off = 128; off >= C; off >>= 1) {
        if (threadIdx.x < off) ls[threadIdx.x] += ls[threadIdx.x + off];
        __syncthreads();
    }
    if (threadIdx.x < C) {
        float f = ls[threadIdx.x] / cg;
        feat[threadIdx.x] = f;
        outp[256 + g * 8 + threadIdx.x] = f;    // features: d_out[256 .. 768)
    }
    __syncthreads();
    if (threadIdx.x < 4) {
        float a = lb[threadIdx.x];
#pragma unroll
        for (int cc = 0; cc < 8; ++cc) a += feat[cc] * lw[cc * 4 + threadIdx.x];
        outp[g * 4 + threadIdx.x] = a;          // logits: d_out[0 .. 256)
    }
}

// ---------------- host ----------------

extern "C" void kernel_launch(void* const* d_in, const int* in_sizes, int n_in,
                              void* d_out, int out_size, void* d_ws, size_t ws_size,
                              hipStream_t stream) {
    const float* x    = (const float*)d_in[0];
    const int*   ei   = (const int*)d_in[1];
    const int*   batch= (const int*)d_in[2];
    const float *w_l1 = (const float*)d_in[3],  *w_r1 = (const float*)d_in[4];
    const float *att1 = (const float*)d_in[5],  *b1   = (const float*)d_in[6];
    const float *gn1w = (const float*)d_in[7],  *gn1b = (const float*)d_in[8],  *gn1s = (const float*)d_in[9];
    const float *w_l2 = (const float*)d_in[10], *w_r2 = (const float*)d_in[11];
    const float *att2 = (const float*)d_in[12], *b2   = (const float*)d_in[13];
    const float *gn2w = (const float*)d_in[14], *gn2b = (const float*)d_in[15], *gn2s = (const float*)d_in[16];
    const float *w_l3 = (const float*)d_in[17], *w_r3 = (const float*)d_in[18];
    const float *att3 = (const float*)d_in[19], *b3   = (const float*)d_in[20];
    const float *gn3w = (const float*)d_in[21], *gn3b = (const float*)d_in[22], *gn3s = (const float*)d_in[23];
    const float *lw   = (const float*)d_in[24], *lb   = (const float*)d_in[25];

    char* ws = (char*)d_ws;
    size_t off = 0;
    auto alloc = [&](size_t bytes) -> void* {
        void* p = ws + off;
        off += (bytes + 255) & ~(size_t)255;
        return p;
    };
    __half* Ah  = (__half*)alloc((size_t)NN * 128 * 2);  // x_l fp16 (GEMM out, attn gather operand)
    __half* Bh  = (__half*)alloc((size_t)NN * 128 * 2);  // attn out fp16 (l1, l3)
    __half* Chh = (__half*)alloc((size_t)NN * 64 * 2);   // attn out fp16 (l2)
    __half* B   = (__half*)alloc((size_t)NN * 128 * 2);  // x_r fp16 (l1, l3)
    __half* Cb  = (__half*)alloc((size_t)NN * 64 * 2);   // x_r fp16 (l2)
    float*  Af  = (float*)alloc((size_t)NN * 8 * 4);     // layer-3 head-mean features
    _Float16* Wf1 = (_Float16*)alloc((size_t)256 * 128 * 2);  // frag-ordered weights l1
    _Float16* Wf2 = (_Float16*)alloc((size_t)128 * 128 * 2);  // l2
    _Float16* Wf3 = (_Float16*)alloc((size_t)64 * 64 * 2);    // l3
    int* rowptr = (int*)alloc((size_t)(NN + 1) * 4);
    unsigned short* colsrc = (unsigned short*)alloc((size_t)ET * 2);
    unsigned int* ebuf = (unsigned int*)alloc((size_t)ET * 4);
    int* bcnt   = (int*)alloc((size_t)NBK * SB * 4);
    int* boff   = (int*)alloc((size_t)NBK * SB * 4);
    int* tot    = (int*)alloc((size_t)NBK * 4);
    int* bpos   = (int*)alloc((size_t)(NG + 1) * 4);
    int* perm   = (int*)alloc((size_t)NN * 4);
    char* zbase = ws + off;                              // everything below gets one memset
    float* sum1 = (float*)alloc((size_t)NG * 128 * 4);
    float* sq1  = (float*)alloc((size_t)NG * 128 * 4);
    float* sum2 = (float*)alloc((size_t)NG * 64 * 4);
    float* sq2  = (float*)alloc((size_t)NG * 64 * 4);
    float* sum3 = (float*)alloc((size_t)NG * 8 * 4);
    float* sq3  = (float*)alloc((size_t)NG * 8 * 4);
    size_t zbytes = (size_t)((ws + off) - zbase);
    (void)hipMemsetAsync(zbase, 0, zbytes, stream);

    k_prep<<<26 + NBK + SB, 256, 0, stream>>>(w_l1, w_r1, w_l2, w_r2, w_l3, w_r3, Wf1, Wf2, Wf3,
                                              batch, bpos, ei, bcnt);
    k_gemm1_scan<<<GD + NBK, 256, 0, stream>>>(x, Wf1, Ah, B, bcnt, boff, tot);
    k_bscatter<<<SB, 1024, 0, stream>>>(ei, tot, boff, ebuf);
    k_bsort<<<NBK, 1024, 0, stream>>>(ebuf, tot, rowptr, colsrc, perm);

    int gA2ep = (NN * H * 2 + 255) / 256;         // EP=2 grids
    int gA1ep = (NN * H + 255) / 256;             // EP=1 grid

    // ---- layer 1: 128 -> 4x32 concat -> 128 (GN params computed inside l2 GEMM)
    k_attn<32, 2, true><<<gA2ep, 256, 0, stream>>>(Ah, B, rowptr, colsrc, perm, att1, b1, Bh);
    k_gnred2<7, 8><<<NG * 8, 256, 0, stream>>>(Bh, bpos, sum1, sq1);

    // ---- layer 2: 128 -> 4x16 concat -> 64 (GN params computed inside l3 GEMM)
    k_dualgemm_n<128, 64><<<GD, 256, 0, stream>>>(Bh, Wf2, Ah, Cb, sum1, sq1, gn1w, gn1b, gn1s, bpos, batch);
    k_attn<16, 2, true><<<gA2ep, 256, 0, stream>>>(Ah, Cb, rowptr, colsrc, perm, att2, b2, Chh);
    k_gnred2<6, 8><<<NG * 8, 256, 0, stream>>>(Chh, bpos, sum2, sq2);

    // ---- layer 3: 64 -> 4x8 mean -> 8, fused tail
    k_dualgemm_n<64, 32><<<GD, 256, 0, stream>>>(Chh, Wf3, Ah, B, sum2, sq2, gn2w, gn2b, gn2s, bpos, batch);
    k_attn<8, 1, false><<<gA1ep, 256, 0, stream>>>(Ah, B, rowptr, colsrc, perm, att3, nullptr, Bh);
    k_headgn<8><<<NG * 8, 256, 0, stream>>>(Bh, b3, bpos, Af, sum3, sq3);
    k_gnpool_final<<<NG, 256, 0, stream>>>(Af, bpos, sum3, sq3, gn3w, gn3b, gn3s, lw, lb, (float*)d_out);
}

// Round 9
// 287.928 us; speedup vs baseline: 1.0619x; 1.0619x over previous
//
#include <hip/hip_runtime.h>
#include <hip/hip_fp16.h>
#include <math.h>

#define NN 50000
#define NE 800000
#define ET (NE + NN)
#define NG 64
#define H 4
#define NBK 196                   // dst buckets (dst >> 8)
#define CH 2048                   // edges per chunk
#define SB ((ET + CH - 1) / CH)   // 416 edge chunks
#define GD ((NN + 63) / 64)       // dualgemm grid (782)

typedef _Float16 half8 __attribute__((ext_vector_type(8)));
typedef _Float16 half4 __attribute__((ext_vector_type(4)));
typedef _Float16 hv2 __attribute__((ext_vector_type(2)));
typedef float floatx4 __attribute__((ext_vector_type(4)));

// ---------------- weight prep device fn ----------------

template <int K, int M2>
__device__ __forceinline__ void wprep_fn(int chunk, const float* __restrict__ Wl, const float* __restrict__ Wr,
                                         _Float16* __restrict__ Wfrag) {
    constexpr int MTOT = 2 * M2, NT = MTOT / 16;
    if (chunk >= MTOT * K / 8) return;
    int lane = chunk & 63, tt = chunk >> 6;
    int t = tt % NT, kt = tt / NT;
    int n = t * 16 + (lane & 15);
    int kb = kt * 32 + (lane >> 4) * 8;
    const float* src = (n < M2) ? (Wl + n) : (Wr + (n - M2));
    half8 h;
#pragma unroll
    for (int j = 0; j < 8; ++j) h[j] = (_Float16)src[(size_t)(kb + j) * M2];
    *(half8*)(Wfrag + (size_t)chunk * 8) = h;
}

// ---------------- fused prep: wprep (26) + bounds (196) + bhist (416) ----------------

__global__ __launch_bounds__(256) void k_prep(const float* __restrict__ Wl1, const float* __restrict__ Wr1,
                                              const float* __restrict__ Wl2, const float* __restrict__ Wr2,
                                              const float* __restrict__ Wl3, const float* __restrict__ Wr3,
                                              _Float16* __restrict__ Wf1, _Float16* __restrict__ Wf2,
                                              _Float16* __restrict__ Wf3,
                                              const int* __restrict__ batch, int* __restrict__ bpos,
                                              const int* __restrict__ ei, int* __restrict__ bcnt) {
    int b = blockIdx.x, t = threadIdx.x;
    if (b < 16) { wprep_fn<128, 128>(b * 256 + t, Wl1, Wr1, Wf1); return; }
    if (b < 24) { wprep_fn<128, 64>((b - 16) * 256 + t, Wl2, Wr2, Wf2); return; }
    if (b < 26) { wprep_fn<64, 32>((b - 24) * 256 + t, Wl3, Wr3, Wf3); return; }
    if (b < 26 + NBK) {
        int i = (b - 26) * 256 + t;
        if (i >= NN) return;
        int cur = batch[i];
        int prev = (i == 0) ? -1 : batch[i - 1];
        for (int g = prev + 1; g <= cur; ++g) bpos[g] = i;
        if (i == NN - 1)
            for (int g = cur + 1; g <= NG; ++g) bpos[g] = NN;
        return;
    }
    // bhist
    __shared__ int hist[NBK];
    int b0 = b - 26 - NBK;
    for (int i = t; i < NBK; i += 256) hist[i] = 0;
    __syncthreads();
#pragma unroll
    for (int pass = 0; pass < CH / 256; ++pass) {
        int e = b0 * CH + pass * 256 + t;
        if (e < ET) {
            int d = (e < NE) ? ei[NE + e] : (e - NE);
            atomicAdd(&hist[d >> 8], 1);
        }
    }
    __syncthreads();
    if (t < NBK) bcnt[t * SB + b0] = hist[t];
}

// ---------------- dualgemm body; A fp16/fp32; optional fused GraphNorm on A
//                  (params computed per-block into LDS from sum/sumsq) ----------------

template <typename AT, bool NORM>
__device__ __forceinline__ half8 load_a8(const AT* __restrict__ ap, const float* pa, const float* pb) {
    if constexpr (NORM) {
        half8 raw = *(const half8*)ap;
        half8 h;
#pragma unroll
        for (int j = 0; j < 8; ++j) {
            float y = fmaf((float)raw[j], pa[j], pb[j]);
            h[j] = (_Float16)fmaxf(y, 0.f);
        }
        return h;
    } else if constexpr (__is_same(AT, _Float16)) {
        return *(const half8*)ap;
    } else {
        const float4* p = (const float4*)ap;
        float4 a = p[0], b = p[1];
        half8 h;
        h[0] = (_Float16)a.x; h[1] = (_Float16)a.y; h[2] = (_Float16)a.z; h[3] = (_Float16)a.w;
        h[4] = (_Float16)b.x; h[5] = (_Float16)b.y; h[6] = (_Float16)b.z; h[7] = (_Float16)b.w;
        return h;
    }
}

template <int K, int M2, typename AT, bool NORM>
__device__ __forceinline__ void dualgemm_body(int blk, int tid, const AT* __restrict__ Ain,
                                              const _Float16* __restrict__ Wfrag,
                                              __half* __restrict__ Ol, __half* __restrict__ Or,
                                              const float* __restrict__ gsum, const float* __restrict__ gsq,
                                              const float* __restrict__ gw, const float* __restrict__ gbb,
                                              const float* __restrict__ gms,
                                              const int* __restrict__ bpos, const int* __restrict__ batch) {
    constexpr int MTOT = 2 * M2;
    constexpr int NT = MTOT / 16;
    constexpr int KT = K / 32;
    constexpr int PK = NORM ? K : 1;      // LDS param table width
    __shared__ float spab[2][8][PK];      // [a|bsh][graph-local][channel]
    int wid = tid >> 6, lane = tid & 63;
    int q = lane >> 4, l15 = lane & 15;
    int r0 = blk * 64 + wid * 16;
    int arow = min(r0 + l15, NN - 1);
    const AT* ap = Ain + (size_t)arow * K + q * 8;
    const float *pa = nullptr, *pb = nullptr;
    if constexpr (NORM) {
        // block rows span graphs [g0, g1]; graphs are ~780 rows so gspan <= 2 in practice
        int rb = blk * 64;
        int g0 = batch[min(rb, NN - 1)];
        int g1 = batch[min(rb + 63, NN - 1)];
        int gspan = min(g1 - g0 + 1, 8);
        for (int i = tid; i < gspan * K; i += 256) {
            int gg = i / K, c = i - gg * K;
            int g = g0 + gg;
            float cg = fmaxf((float)(bpos[g + 1] - bpos[g]), 1.f);
            float mu = gsum[(size_t)g * K + c] / cg;
            float ex2 = gsq[(size_t)g * K + c] / cg;
            float s_ = gms[c];
            float var = ex2 - s_ * (2.f - s_) * mu * mu;
            float a = rsqrtf(var + 1e-5f) * gw[c];
            spab[0][gg][c] = a;
            spab[1][gg][c] = gbb[c] - mu * s_ * a;
        }
        __syncthreads();
        int gg = min(batch[arow] - g0, 7);
        pa = &spab[0][gg][q * 8];
        pb = &spab[1][gg][q * 8];
    }

    floatx4 acc[NT];
#pragma unroll
    for (int t = 0; t < NT; ++t) acc[t] = (floatx4){0.f, 0.f, 0.f, 0.f};

#pragma unroll
    for (int kt = 0; kt < KT; ++kt) {
        half8 a8 = load_a8<AT, NORM>(ap + kt * 32, pa + (NORM ? kt * 32 : 0), pb + (NORM ? kt * 32 : 0));
        const _Float16* wp = Wfrag + ((size_t)(kt * NT) * 64 + lane) * 8;
#pragma unroll
        for (int t = 0; t < NT; ++t) {
            half8 b8 = *(const half8*)(wp + (size_t)t * 64 * 8);
            acc[t] = __builtin_amdgcn_mfma_f32_16x16x32_f16(a8, b8, acc[t], 0, 0, 0);
        }
    }

#pragma unroll
    for (int t = 0; t < NT; ++t) {
        int cn = t * 16 + l15;
#pragma unroll
        for (int reg = 0; reg < 4; ++reg) {
            int r = r0 + q * 4 + reg;
            if (r < NN) {
                if (cn < M2) Ol[(size_t)r * M2 + cn] = __float2half(acc[t][reg]);
                else         Or[(size_t)r * M2 + (cn - M2)] = __float2half(acc[t][reg]);
            }
        }
    }
}

template <int K, int M2>
__global__ __launch_bounds__(256) void k_dualgemm_n(const __half* __restrict__ Ain,
                                                    const _Float16* __restrict__ Wfrag,
                                                    __half* __restrict__ Ol, __half* __restrict__ Or,
                                                    const float* __restrict__ gsum, const float* __restrict__ gsq,
                                                    const float* __restrict__ gw, const float* __restrict__ gbb,
                                                    const float* __restrict__ gms,
                                                    const int* __restrict__ bpos, const int* __restrict__ batch) {
    dualgemm_body<K, M2, _Float16, true>(blockIdx.x, threadIdx.x, (const _Float16*)Ain, Wfrag, Ol, Or,
                                         gsum, gsq, gw, gbb, gms, bpos, batch);
}

// ---------------- bscanA device fn: pair-scan of SB(416) chunk-counts per bucket ----------------

__device__ __forceinline__ void bscanA_fn(int b, int t, const int* __restrict__ bcnt,
                                          int* __restrict__ boff, int* __restrict__ tot) {
    __shared__ int lds[256];
    int i0 = 2 * t, i1 = 2 * t + 1;
    int v0 = (i0 < SB) ? bcnt[b * SB + i0] : 0;
    int v1 = (i1 < SB) ? bcnt[b * SB + i1] : 0;
    int pair = v0 + v1;
    lds[t] = pair;
    __syncthreads();
    for (int off = 1; off < 256; off <<= 1) {
        int y = (t >= off) ? lds[t - off] : 0;
        __syncthreads();
        lds[t] += y;
        __syncthreads();
    }
    int excl = lds[t] - pair;
    if (i0 < SB) boff[b * SB + i0] = excl;
    if (i1 < SB) boff[b * SB + i1] = excl + v0;
    if (t == 255) tot[b] = lds[255];
}

// ---- fused: dualgemm l1 (782 blocks, fp32 input) + bscanA (196 blocks)

__global__ __launch_bounds__(256) void k_gemm1_scan(const float* __restrict__ x, const _Float16* __restrict__ Wf1,
                                                    __half* __restrict__ Ol, __half* __restrict__ Or,
                                                    const int* __restrict__ bcnt, int* __restrict__ boff,
                                                    int* __restrict__ tot) {
    if (blockIdx.x < GD)
        dualgemm_body<128, 128, float, false>(blockIdx.x, threadIdx.x, x, Wf1, Ol, Or,
                                              nullptr, nullptr, nullptr, nullptr, nullptr, nullptr, nullptr);
    else
        bscanA_fn(blockIdx.x - GD, threadIdx.x, bcnt, boff, tot);
}

// ---------------- CSR: scatter into bucket-major ebuf (1024 threads) ----------------

__device__ __forceinline__ void edge_sd(int e, const int* __restrict__ ei, int& s, int& d) {
    if (e < NE) { s = ei[e]; d = ei[NE + e]; } else { s = e - NE; d = s; }
}

__global__ __launch_bounds__(1024) void k_bscatter(const int* __restrict__ ei, const int* __restrict__ tot,
                                                   const int* __restrict__ boff, unsigned int* __restrict__ ebuf) {
    __shared__ int eb[256];
    __shared__ int cur[NBK];
    int b0 = blockIdx.x, t = threadIdx.x;
    int v = (t < NBK) ? tot[t] : 0;
    if (t < 256) eb[t] = v;
    __syncthreads();
    for (int off = 1; off < 256; off <<= 1) {
        int y = (t >= off && t < 256) ? eb[t - off] : 0;
        __syncthreads();
        if (t < 256) eb[t] += y;
        __syncthreads();
    }
    if (t < NBK) cur[t] = (eb[t] - v) + boff[t * SB + b0];
    __syncthreads();
#pragma unroll
    for (int pass = 0; pass < CH / 1024; ++pass) {
        int e = b0 * CH + pass * 1024 + t;
        if (e < ET) {
            int s, d;
            edge_sd(e, ei, s, d);
            int pos = atomicAdd(&cur[d >> 8], 1);
            ebuf[pos] = ((unsigned)s << 16) | (unsigned)(d & 255);
        }
    }
}

// ---------------- CSR: per-bucket exact-dst counting sort -> rowptr + colsrc (1024 threads) ----------------

__global__ __launch_bounds__(1024) void k_bsort(const unsigned int* __restrict__ ebuf,
                                                const int* __restrict__ tot,
                                                int* __restrict__ rowptr, unsigned short* __restrict__ colsrc) {
    __shared__ int eb[256];
    __shared__ int sbase;
    __shared__ int cnt2[256];
    __shared__ int sc[256];
    __shared__ int cur2[256];
    int b = blockIdx.x, t = threadIdx.x;
    int v = (t < NBK) ? tot[t] : 0;
    if (t < 256) eb[t] = v;
    __syncthreads();
    for (int off = 1; off < 256; off <<= 1) {
        int y = (t >= off && t < 256) ? eb[t - off] : 0;
        __syncthreads();
        if (t < 256) eb[t] += y;
        __syncthreads();
    }
    if (t == b) sbase = eb[t] - v;   // b < NBK <= 255
    __syncthreads();
    int base = sbase, n = tot[b];
    if (t < 256) cnt2[t] = 0;
    __syncthreads();
    for (int i = t; i < n; i += 1024) atomicAdd(&cnt2[ebuf[base + i] & 255], 1);
    __syncthreads();
    if (t < 256) sc[t] = cnt2[t];
    __syncthreads();
    for (int off = 1; off < 256; off <<= 1) {
        int y = (t >= off && t < 256) ? sc[t - off] : 0;
        __syncthreads();
        if (t < 256) sc[t] += y;
        __syncthreads();
    }
    if (t < 256) {
        int cv = cnt2[t];
        int excl = sc[t] - cv;
        int d = b * 256 + t;
        if (d < NN) rowptr[d] = base + excl;
        cur2[t] = excl;
    }
    if (b == 0 && t == 0) rowptr[NN] = ET;
    __syncthreads();
    for (int i = t; i < n; i += 1024) {
        unsigned u = ebuf[base + i];
        int pos = atomicAdd(&cur2[u & 255], 1);
        colsrc[base + pos] = (unsigned short)(u >> 16);
    }
}

// ---------------- GATv2 attention: channel-split + packed fp16 + no-max softmax, fp16 output ----------------

template <int CP> struct HVec { hv2 h2[CP / 2]; };

template <int CP>
__device__ __forceinline__ HVec<CP> load_hv(const __half* __restrict__ p) {
    HVec<CP> r;
    if constexpr (CP == 16) {
        float4* rp = (float4*)&r;
        rp[0] = ((const float4*)p)[0];
        rp[1] = ((const float4*)p)[1];
    } else if constexpr (CP == 8) {
        float4 t = *(const float4*)p; r = *(HVec<CP>*)&t;
    } else if constexpr (CP == 4) {
        float2 t = *(const float2*)p; r = *(HVec<CP>*)&t;
    } else {
        r.h2[0] = *(const hv2*)p;
    }
    return r;
}

template <int C, int EP, bool CONCAT>
__global__ __launch_bounds__(256) void k_attn(const __half* __restrict__ xl, const __half* __restrict__ xr,
                                              const int* __restrict__ rowptr,
                                              const unsigned short* __restrict__ colsrc,
                                              const float* __restrict__ att, const float* __restrict__ bias,
                                              __half* __restrict__ out) {
    constexpr int CP = C / EP;
    constexpr int LEP = (EP == 4) ? 2 : ((EP == 2) ? 1 : 0);
    int t = blockIdx.x * 256 + threadIdx.x;
    int part = t & (EP - 1);
    int nh = t >> LEP;
    if (nh >= NN * H) return;
    int node = nh >> 2, h = nh & 3;           // H == 4
    int cbase = h * C + part * CP;
    hv2 xrr2[CP / 2], attv2[CP / 2];
    float acc[CP];
    {
        HVec<CP> xrv = load_hv<CP>(xr + (size_t)node * (H * C) + cbase);
        const float* q = att + cbase;
#pragma unroll
        for (int j = 0; j < CP / 2; ++j) {
            xrr2[j] = xrv.h2[j];
            attv2[j] = (hv2){(_Float16)q[2 * j], (_Float16)q[2 * j + 1]};
        }
#pragma unroll
        for (int c = 0; c < CP; ++c) acc[c] = 0.f;
    }
    float denom = 0.f;
    int beg = rowptr[node], end = rowptr[node + 1];

    auto process = [&](const HVec<CP>& xv) {
        float part_s = 0.f;
#pragma unroll
        for (int j = 0; j < CP / 2; ++j) {
            hv2 z = xv.h2[j] + xrr2[j];
            hv2 l = __builtin_elementwise_max(z, z * (_Float16)0.2f);   // leaky_relu
            part_s = __builtin_amdgcn_fdot2(l, attv2[j], part_s, false);
        }
        float score = part_s;
#pragma unroll
        for (int mask = 1; mask < EP; mask <<= 1) score += __shfl_xor(score, mask, 64);
        float w = __expf(score);
        denom += w;
        const _Float16* xh = (const _Float16*)&xv;
#pragma unroll
        for (int c = 0; c < CP; ++c) acc[c] = fmaf(w, (float)xh[c], acc[c]);
    };

    int idx = beg;
    // 8-wide main loop: issue all 8 gathers before consuming (MLP for latency-bound gather)
    for (; idx + 8 <= end; idx += 8) {
        int s[8];
#pragma unroll
        for (int u = 0; u < 8; ++u) s[u] = colsrc[idx + u];
        HVec<CP> xv[8];
#pragma unroll
        for (int u = 0; u < 8; ++u) xv[u] = load_hv<CP>(xl + (size_t)s[u] * (H * C) + cbase);
#pragma unroll
        for (int u = 0; u < 8; ++u) process(xv[u]);
    }
    for (; idx + 4 <= end; idx += 4) {
        int s0 = colsrc[idx], s1 = colsrc[idx + 1], s2 = colsrc[idx + 2], s3 = colsrc[idx + 3];
        HVec<CP> xv0 = load_hv<CP>(xl + (size_t)s0 * (H * C) + cbase);
        HVec<CP> xv1 = load_hv<CP>(xl + (size_t)s1 * (H * C) + cbase);
        HVec<CP> xv2 = load_hv<CP>(xl + (size_t)s2 * (H * C) + cbase);
        HVec<CP> xv3 = load_hv<CP>(xl + (size_t)s3 * (H * C) + cbase);
        process(xv0);
        process(xv1);
        process(xv2);
        process(xv3);
    }
    for (; idx < end; ++idx) {
        int s = colsrc[idx];
        HVec<CP> xv = load_hv<CP>(xl + (size_t)s * (H * C) + cbase);
        process(xv);
    }

    float inv = 1.f / denom;
    _Float16* op = (_Float16*)out + (size_t)node * (H * C) + cbase;
    _Float16 hv[CP];
#pragma unroll
    for (int c = 0; c < CP; ++c) {
        float v = acc[c] * inv;
        if (CONCAT) v += bias[cbase + c];
        hv[c] = (_Float16)v;
    }
    if constexpr (CP >= 8) {
#pragma unroll
        for (int j = 0; j < CP / 8; ++j) *(half8*)(op + 8 * j) = *(half8*)(hv + 8 * j);
    } else if constexpr (CP == 4) {
        *(half4*)op = *(half4*)hv;
    } else {
        *(hv2*)op = *(hv2*)hv;
    }
}

// ---------------- GraphNorm reduce (fp16 input): one block per (graph, segment) ----------------

template <int LOGC, int SPLIT>
__global__ __launch_bounds__(256) void k_gnred2(const __half* __restrict__ h, const int* __restrict__ bpos,
                                                float* __restrict__ sum, float* __restrict__ sumsq) {
    constexpr int C = 1 << LOGC;
    constexpr int RG = 256 >> LOGC;      // row-groups per block
    int g = blockIdx.x / SPLIT, s = blockIdx.x % SPLIT;
    int c = threadIdx.x & (C - 1);
    int rg = threadIdx.x >> LOGC;
    int b0 = bpos[g], b1 = bpos[g + 1];
    int n = b1 - b0;
    int seg = (n + SPLIT - 1) / SPLIT;
    int r0 = b0 + s * seg;
    int r1 = min(r0 + seg, b1);
    float sv = 0.f, ssv = 0.f;
    for (int r = r0 + rg; r < r1; r += RG) {
        float x = __half2float(h[(size_t)r * C + c]);
        sv += x; ssv += x * x;
    }
    __shared__ float ls[256], lss[256];
    ls[threadIdx.x] = sv; lss[threadIdx.x] = ssv;
    __syncthreads();
    for (int off = 128; off >= C; off >>= 1) {
        if (threadIdx.x < off) {
            ls[threadIdx.x] += ls[threadIdx.x + off];
            lss[threadIdx.x] += lss[threadIdx.x + off];
        }
        __syncthreads();
    }
    if (threadIdx.x < C) {
        atomicAdd(&sum[g * C + threadIdx.x], ls[threadIdx.x]);
        atomicAdd(&sumsq[g * C + threadIdx.x], lss[threadIdx.x]);
    }
}

// ---------------- fused layer-3 tail: head-mean + bias + GN3 stats ----------------

template <int SPLIT>
__global__ __launch_bounds__(256) void k_headgn(const __half* __restrict__ tmp, const float* __restrict__ b3,
                                                const int* __restrict__ bpos, float* __restrict__ Af,
                                                float* __restrict__ sum, float* __restrict__ sumsq) {
    constexpr int C = 8, RG = 32;
    int g = blockIdx.x / SPLIT, s = blockIdx.x % SPLIT;
    int c = threadIdx.x & 7;
    int rg = threadIdx.x >> 3;
    int b0 = bpos[g], b1 = bpos[g + 1];
    int n = b1 - b0;
    int seg = (n + SPLIT - 1) / SPLIT;
    int r0 = b0 + s * seg;
    int r1 = min(r0 + seg, b1);
    float bias = b3[c];
    float sv = 0.f, ssv = 0.f;
    for (int r = r0 + rg; r < r1; r += RG) {
        const __half* p = tmp + (size_t)r * 32 + c;
        float v = 0.25f * (__half2float(p[0]) + __half2float(p[8]) +
                           __half2float(p[16]) + __half2float(p[24])) + bias;
        Af[(size_t)r * C + c] = v;
        sv += v; ssv += v * v;
    }
    __shared__ float ls[256], lss[256];
    ls[threadIdx.x] = sv; lss[threadIdx.x] = ssv;
    __syncthreads();
    for (int off = 128; off >= C; off >>= 1) {
        if (threadIdx.x < off) {
            ls[threadIdx.x] += ls[threadIdx.x + off];
            lss[threadIdx.x] += lss[threadIdx.x + off];
        }
        __syncthreads();
    }
    if (threadIdx.x < C) {
        atomicAdd(&sum[g * C + threadIdx.x], ls[threadIdx.x]);
        atomicAdd(&sumsq[g * C + threadIdx.x], lss[threadIdx.x]);
    }
}

// ---------------- GN3 normalize + relu + pool + mean + linear head (one block per graph) ----------------

__global__ __launch_bounds__(256) void k_gnpool_final(const float* __restrict__ Af, const int* __restrict__ bpos,
                                                      const float* __restrict__ sum, const float* __restrict__ sumsq,
                                                      const float* __restrict__ w,
                                                      const float* __restrict__ b, const float* __restrict__ ms,
                                                      const float* __restrict__ lw, const float* __restrict__ lb,
                                                      float* __restrict__ outp) {
    constexpr int C = 8, RG = 32;
    int g = blockIdx.x;
    int c = threadIdx.x & 7;
    int rg = threadIdx.x >> 3;
    int b0 = bpos[g], b1 = bpos[g + 1];
    int n = b1 - b0;
    float cg = fmaxf((float)n, 1.f);
    float mu = sum[g * C + c] / cg;
    float ex2 = sumsq[g * C + c] / cg;
    float s_ = ms[c];
    float var = ex2 - (2.f * s_ - s_ * s_) * mu * mu;
    float rs = rsqrtf(var + 1e-5f) * w[c];
    float bb = b[c], mus = mu * s_;
    float pv = 0.f;
    for (int r = b0 + rg; r < b1; r += RG) {
        float y = fmaxf((Af[(size_t)r * C + c] - mus) * rs + bb, 0.f);
        pv += y;
    }
    __shared__ float ls[256];
    __shared__ float feat[8];
    ls[threadIdx.x] = pv;
    __syncthreads();
    for (int off = 128; off >= C; off >>= 1) {
        if (threadIdx.x < off) ls[threadIdx.x] += ls[threadIdx.x + off];
        __syncthreads();
    }
    if (threadIdx.x < C) {
        float f = ls[threadIdx.x] / cg;
        feat[threadIdx.x] = f;
        outp[256 + g * 8 + threadIdx.x] = f;    // features: d_out[256 .. 768)
    }
    __syncthreads();
    if (threadIdx.x < 4) {
        float a = lb[threadIdx.x];
#pragma unroll
        for (int cc = 0; cc < 8; ++cc) a += feat[cc] * lw[cc * 4 + threadIdx.x];
        outp[g * 4 + threadIdx.x] = a;          // logits: d_out[0 .. 256)
    }
}

// ---------------- host ----------------

extern "C" void kernel_launch(void* const* d_in, const int* in_sizes, int n_in,
                              void* d_out, int out_size, void* d_ws, size_t ws_size,
                              hipStream_t stream) {
    const float* x    = (const float*)d_in[0];
    const int*   ei   = (const int*)d_in[1];
    const int*   batch= (const int*)d_in[2];
    const float *w_l1 = (const float*)d_in[3],  *w_r1 = (const float*)d_in[4];
    const float *att1 = (const float*)d_in[5],  *b1   = (const float*)d_in[6];
    const float *gn1w = (const float*)d_in[7],  *gn1b = (const float*)d_in[8],  *gn1s = (const float*)d_in[9];
    const float *w_l2 = (const float*)d_in[10], *w_r2 = (const float*)d_in[11];
    const float *att2 = (const float*)d_in[12], *b2   = (const float*)d_in[13];
    const float *gn2w = (const float*)d_in[14], *gn2b = (const float*)d_in[15], *gn2s = (const float*)d_in[16];
    const float *w_l3 = (const float*)d_in[17], *w_r3 = (const float*)d_in[18];
    const float *att3 = (const float*)d_in[19], *b3   = (const float*)d_in[20];
    const float *gn3w = (const float*)d_in[21], *gn3b = (const float*)d_in[22], *gn3s = (const float*)d_in[23];
    const float *lw   = (const float*)d_in[24], *lb   = (const float*)d_in[25];

    char* ws = (char*)d_ws;
    size_t off = 0;
    auto alloc = [&](size_t bytes) -> void* {
        void* p = ws + off;
        off += (bytes + 255) & ~(size_t)255;
        return p;
    };
    __half* Ah  = (__half*)alloc((size_t)NN * 128 * 2);  // x_l fp16 (GEMM out, attn gather operand)
    __half* Bh  = (__half*)alloc((size_t)NN * 128 * 2);  // attn out fp16 (l1, l3)
    __half* Chh = (__half*)alloc((size_t)NN * 64 * 2);   // attn out fp16 (l2)
    __half* B   = (__half*)alloc((size_t)NN * 128 * 2);  // x_r fp16 (l1, l3)
    __half* Cb  = (__half*)alloc((size_t)NN * 64 * 2);   // x_r fp16 (l2)
    float*  Af  = (float*)alloc((size_t)NN * 8 * 4);     // layer-3 head-mean features
    _Float16* Wf1 = (_Float16*)alloc((size_t)256 * 128 * 2);  // frag-ordered weights l1
    _Float16* Wf2 = (_Float16*)alloc((size_t)128 * 128 * 2);  // l2
    _Float16* Wf3 = (_Float16*)alloc((size_t)64 * 64 * 2);    // l3
    int* rowptr = (int*)alloc((size_t)(NN + 1) * 4);
    unsigned short* colsrc = (unsigned short*)alloc((size_t)ET * 2);
    unsigned int* ebuf = (unsigned int*)alloc((size_t)ET * 4);
    int* bcnt   = (int*)alloc((size_t)NBK * SB * 4);
    int* boff   = (int*)alloc((size_t)NBK * SB * 4);
    int* tot    = (int*)alloc((size_t)NBK * 4);
    int* bpos   = (int*)alloc((size_t)(NG + 1) * 4);
    char* zbase = ws + off;                              // everything below gets one memset
    float* sum1 = (float*)alloc((size_t)NG * 128 * 4);
    float* sq1  = (float*)alloc((size_t)NG * 128 * 4);
    float* sum2 = (float*)alloc((size_t)NG * 64 * 4);
    float* sq2  = (float*)alloc((size_t)NG * 64 * 4);
    float* sum3 = (float*)alloc((size_t)NG * 8 * 4);
    float* sq3  = (float*)alloc((size_t)NG * 8 * 4);
    size_t zbytes = (size_t)((ws + off) - zbase);
    (void)hipMemsetAsync(zbase, 0, zbytes, stream);

    k_prep<<<26 + NBK + SB, 256, 0, stream>>>(w_l1, w_r1, w_l2, w_r2, w_l3, w_r3, Wf1, Wf2, Wf3,
                                              batch, bpos, ei, bcnt);
    k_gemm1_scan<<<GD + NBK, 256, 0, stream>>>(x, Wf1, Ah, B, bcnt, boff, tot);
    k_bscatter<<<SB, 1024, 0, stream>>>(ei, tot, boff, ebuf);
    k_bsort<<<NBK, 1024, 0, stream>>>(ebuf, tot, rowptr, colsrc);

    int gA4ep = (NN * H * 4 + 255) / 256;         // EP=4 grid (3125)
    int gA2ep = (NN * H * 2 + 255) / 256;         // EP=2 grid (1563)
    int gA1ep = (NN * H + 255) / 256;             // EP=1 grid (782)

    // ---- layer 1: 128 -> 4x32 concat -> 128 (EP=4: 2x waves for latency hiding; GN params inside l2 GEMM)
    k_attn<32, 4, true><<<gA4ep, 256, 0, stream>>>(Ah, B, rowptr, colsrc, att1, b1, Bh);
    k_gnred2<7, 8><<<NG * 8, 256, 0, stream>>>(Bh, bpos, sum1, sq1);

    // ---- layer 2: 128 -> 4x16 concat -> 64 (GN params computed inside l3 GEMM)
    k_dualgemm_n<128, 64><<<GD, 256, 0, stream>>>(Bh, Wf2, Ah, Cb, sum1, sq1, gn1w, gn1b, gn1s, bpos, batch);
    k_attn<16, 2, true><<<gA2ep, 256, 0, stream>>>(Ah, Cb, rowptr, colsrc, att2, b2, Chh);
    k_gnred2<6, 8><<<NG * 8, 256, 0, stream>>>(Chh, bpos, sum2, sq2);

    // ---- layer 3: 64 -> 4x8 mean -> 8, fused tail
    k_dualgemm_n<64, 32><<<GD, 256, 0, stream>>>(Chh, Wf3, Ah, B, sum2, sq2, gn2w, gn2b, gn2s, bpos, batch);
    k_attn<8, 1, false><<<gA1ep, 256, 0, stream>>>(Ah, B, rowptr, colsrc, att3, nullptr, Bh);
    k_headgn<8><<<NG * 8, 256, 0, stream>>>(Bh, b3, bpos, Af, sum3, sq3);
    k_gnpool_final<<<NG, 256, 0, stream>>>(Af, bpos, sum3, sq3, gn3w, gn3b, gn3s, lw, lb, (float*)d_out);
}